// Round 18
// baseline (222.503 us; speedup 1.0000x reference)
//
#include <hip/hip_runtime.h>
#include <hip/hip_bf16.h>

typedef _Float16 half8_t __attribute__((ext_vector_type(8)));
typedef _Float16 half4_t __attribute__((ext_vector_type(4)));
typedef _Float16 half2_t __attribute__((ext_vector_type(2)));
typedef float    f32x4   __attribute__((ext_vector_type(4)));
typedef float    f32x16  __attribute__((ext_vector_type(16)));

#define CDIM 512
#define NHEAD 8
#define HD 64
#define NTOK 512
#define NWIN 64
#define TC 1536  // 3*C

// raw v_exp_f32 (2^x); softmax inputs <= 11.5, large-negative underflows to 0.
__device__ __forceinline__ float fexp2(float x) {
  float r;
  asm("v_exp_f32 %0, %1" : "=v"(r) : "v"(x));
  return r;
}

// global->LDS direct DMA, 16B per lane, wave-uniform LDS base (m97 pattern)
#define GLL16(g, l)                                                        \
  __builtin_amdgcn_global_load_lds((const __attribute__((address_space(1))) void*)(g), \
                                   (__attribute__((address_space(3))) void*)(l), 16, 0, 0)

// ws panel layout: per (local window w): 24 panels of 32768 halfs (65536 B)
//   panel (w*24 + 0*8 + h): Q*log2e [n][d]  (later overwritten by attention output [n][d])
//   panel (w*24 + 1*8 + h): K  [n][d]
//   panel (w*24 + 2*8 + h): V key-permuted: [kg(32)][hh(2)][d(64)][e(8)]
//     key n -> kg=n>>4, hh=(n>>2)&1, e=(n&3)+4*((n>>3)&1)
// x16 / wqkvT BLOCKED layout: tile(rb,ks) = rows [rb*16,+16) x k [ks*32,+32),
//   contiguous 1024B: halfs offset = rb*8192 + ks*512 + r4*32 + c16*8.

// ---------------- x fp32 -> fp16, blocked tiles, coalesced 1024B tile writes ----------------
__global__ __launch_bounds__(256) void cvt_x(const float* __restrict__ x,
                                             _Float16* __restrict__ x16) {
  const int rb = blockIdx.x;
  const int l = threadIdx.x & 63, wv = threadIdx.x >> 6;
  const int r4 = l >> 2, c = l & 3;
  const float* src = x + (size_t)rb * 16 * 512 + (size_t)r4 * 512;
  _Float16* dst = x16 + (size_t)rb * 8192;
#pragma unroll
  for (int i = 0; i < 4; ++i) {
    int ks = wv * 4 + i;
    const float4 v0 = *(const float4*)(src + ks * 32 + c * 8);
    const float4 v1 = *(const float4*)(src + ks * 32 + c * 8 + 4);
    half8_t hv = {(_Float16)v0.x, (_Float16)v0.y, (_Float16)v0.z, (_Float16)v0.w,
                  (_Float16)v1.x, (_Float16)v1.y, (_Float16)v1.z, (_Float16)v1.w};
    *(half8_t*)(dst + ks * 512 + r4 * 32 + c * 8) = hv;  // wave: 1024B contiguous
  }
}

// ---------------- prep: fp32 -> fp16 transposes (wqkvT blocked, wprojT linear) ----------------
__global__ __launch_bounds__(256) void prep_weights(
    const float* __restrict__ wqkv, const float* __restrict__ wproj,
    _Float16* __restrict__ wqkvT, _Float16* __restrict__ wprojT) {
  __shared__ _Float16 T[64 * 65];
  int b = blockIdx.x;
  const float* src; _Float16* dst; int Cc, r0, c0; bool blocked;
  if (b < 192) {
    src = wqkv; dst = wqkvT; Cc = 1536; blocked = true;
    c0 = (b % 24) * 64; r0 = (b / 24) * 64;
  } else {
    b -= 192; src = wproj; dst = wprojT; Cc = 512; blocked = false;
    c0 = (b & 7) * 64; r0 = (b >> 3) * 64;
  }
  const int t = threadIdx.x;
#pragma unroll
  for (int i = 0; i < 16; ++i) {
    int idx = i * 256 + t, rr = idx >> 6, cc = idx & 63;
    T[rr * 65 + cc] = (_Float16)src[(size_t)(r0 + rr) * Cc + c0 + cc];
  }
  __syncthreads();
#pragma unroll
  for (int i = 0; i < 2; ++i) {
    int idx = i * 256 + t, ol = idx >> 3, c8 = idx & 7;
    half8_t vv;
#pragma unroll
    for (int e = 0; e < 8; ++e) vv[e] = T[(c8 * 8 + e) * 65 + ol];
    int o = c0 + ol, k = r0 + c8 * 8;
    if (blocked)
      *(half8_t*)(dst + (size_t)(o >> 4) * 8192 + (size_t)(k >> 5) * 512 +
                  (o & 15) * 32 + ((k & 31) >> 3) * 8) = vv;
    else
      *(half8_t*)(dst + (size_t)o * 512 + k) = vv;
  }
}

// ---------------- GEMM1 v7: 128x128 tile, 4 waves, BK=32, ring-3, 3 blocks/CU ----------------
// Full-cache-line staging (blocked sources); swizzle pair verified r13/r14.
__global__ __launch_bounds__(256, 3) void gemm1_qkv(
    const _Float16* __restrict__ x16,
    const _Float16* __restrict__ wT,
    const float* __restrict__ bias,
    _Float16* __restrict__ qkv) {
  __shared__ __align__(16) char ring[3 * 16384];  // 48KB; epilogue reuses as C-tile (32KB)
  char* ringB = ring;
  const int tid = threadIdx.x;
  const int l = tid & 63;
  const int wid = tid >> 6;               // 0..3
  const int wr = wid >> 1, wc = wid & 1;  // 2M x 2N waves; per-wave 64x64 output
  const int lr = l & 15, g = l >> 4;
  const int koff = ((g ^ ((lr >> 1) & 3)) << 4);
  const int m0 = blockIdx.x * 128;
  const int cb = blockIdx.y * 128;        // channel base 0..1408
  const int j = cb >> 9;                  // 0=Q 1=K 2=V

  const int r4 = l >> 2;
  const int schk = (l & 3) ^ ((r4 >> 1) & 3);
  const size_t laneT = (size_t)r4 * 64 + (size_t)schk * 16;
  const size_t aTile = ((size_t)(blockIdx.x * 8 + wid * 2)) * 16384 + laneT;
  const size_t bTile = ((size_t)(blockIdx.y * 8 + wid * 2)) * 16384 + laneT;

#define ISSUE_G1(KS)                                                              \
  {                                                                               \
    char* sa = ringB + ((KS) % 3) * 16384;                                        \
    char* sbB = sa + 8192;                                                        \
    _Pragma("unroll") for (int i = 0; i < 2; ++i) {                               \
      GLL16((const char*)x16 + aTile + (size_t)i * 16384 + (size_t)(KS)*1024,     \
            sa + wid * 2048 + i * 1024);                                          \
      GLL16((const char*)wT + bTile + (size_t)i * 16384 + (size_t)(KS)*1024,      \
            sbB + wid * 2048 + i * 1024);                                         \
    }                                                                             \
  }

  ISSUE_G1(0) ISSUE_G1(1)  // outstanding: 8 (4/slot/thread)

  f32x4 acc[4][4] = {};

#define GITER(KS, NW)                                                             \
  {                                                                               \
    asm volatile("s_waitcnt vmcnt(" NW ")" ::: "memory");                         \
    __builtin_amdgcn_sched_barrier(0);                                            \
    asm volatile("s_barrier" ::: "memory");                                       \
    if ((KS) + 2 < 16) ISSUE_G1((KS) + 2)                                         \
    char* sa = ringB + ((KS) % 3) * 16384;                                        \
    char* sbB = sa + 8192;                                                        \
    half8_t a[4], b[4];                                                           \
    _Pragma("unroll") for (int mt = 0; mt < 4; ++mt)                              \
        a[mt] = *(const half8_t*)(sa + (wr * 64 + mt * 16 + lr) * 64 + koff);     \
    _Pragma("unroll") for (int nt = 0; nt < 4; ++nt)                              \
        b[nt] = *(const half8_t*)(sbB + (wc * 64 + nt * 16 + lr) * 64 + koff);    \
    __builtin_amdgcn_s_setprio(1);                                                \
    _Pragma("unroll") for (int mt = 0; mt < 4; ++mt)                              \
        _Pragma("unroll") for (int nt = 0; nt < 4; ++nt)                          \
            acc[mt][nt] =                                                         \
                __builtin_amdgcn_mfma_f32_16x16x32_f16(a[mt], b[nt], acc[mt][nt], 0, 0, 0); \
    __builtin_amdgcn_s_setprio(0);                                                \
  }

  GITER(0, "4")  GITER(1, "4")  GITER(2, "4")  GITER(3, "4")
  GITER(4, "4")  GITER(5, "4")  GITER(6, "4")  GITER(7, "4")
  GITER(8, "4")  GITER(9, "4")  GITER(10, "4") GITER(11, "4")
  GITER(12, "4") GITER(13, "4") GITER(14, "4") GITER(15, "0")

  if (j == 2) {  // V: key-permuted panels, 8B stores
#pragma unroll
    for (int nt = 0; nt < 4; ++nt) {
      const int ch = cb + wc * 64 + nt * 16 + lr;
      const int h = (ch >> 6) & 7, d = ch & 63;
      const float bvs = bias[ch];
#pragma unroll
      for (int mt = 0; mt < 4; ++mt) {
        const int row = m0 + wr * 64 + mt * 16 + g * 4;
        const int wL = row >> 9, n = row & 511;
        _Float16* panel = qkv + ((size_t)(wL * 24 + 16 + h) << 15);
        const int kg = n >> 4, hh = (n >> 2) & 1, e4 = (n & 8) >> 1;
        half4_t pk = {(_Float16)(acc[mt][nt][0] + bvs), (_Float16)(acc[mt][nt][1] + bvs),
                      (_Float16)(acc[mt][nt][2] + bvs), (_Float16)(acc[mt][nt][3] + bvs)};
        *(half4_t*)(panel + ((size_t)(kg * 2 + hh) * 64 + d) * 8 + e4) = pk;
      }
    }
  } else {  // Q/K: acc -> swizzled LDS C-tile (reuse ring) -> coalesced 16B stores
    __syncthreads();
    const float scl = (j == 0) ? 1.44269504f : 1.0f;
    char* CB = ringB;
#pragma unroll
    for (int nt = 0; nt < 4; ++nt) {
      const int chl = wc * 64 + nt * 16 + lr;
      const float bvs = bias[cb + chl];
#pragma unroll
      for (int mt = 0; mt < 4; ++mt) {
#pragma unroll
        for (int r = 0; r < 4; ++r) {
          int nl = wr * 64 + mt * 16 + g * 4 + r;
          *(_Float16*)(CB + nl * 256 + ((chl * 2) ^ ((nl & 7) << 5))) =
              (_Float16)((acc[mt][nt][r] + bvs) * scl);
        }
      }
    }
    __syncthreads();
#pragma unroll
    for (int i = 0; i < 8; ++i) {
      int idx = i * 256 + tid, nl = idx >> 4, c8 = idx & 15;
      half8_t vv = *(const half8_t*)(CB + nl * 256 + ((c8 * 16) ^ ((nl & 7) << 5)));
      int chg = cb + c8 * 8;
      int h = (chg >> 6) & 7, d = chg & 63;
      int ng = m0 + nl, wL = ng >> 9, nn = ng & 511;
      _Float16* panel = qkv + ((size_t)(wL * 24 + j * 8 + h) << 15);
      *(half8_t*)(panel + (size_t)nn * 64 + d) = vv;
    }
  }
}

// ---------------- attention v11: 8-wave blocks, LDS K/V ring-8, depth-7 prefetch ----------------
// grid = dim3(nw*8, 2). Ring 8 x 8KB = 64KB; 7 slots outstanding (56KB in flight).
__global__ __launch_bounds__(512) void attn_win(_Float16* __restrict__ qkv) {
  __shared__ __align__(16) char ring[8 * 8192];
  char* ringB = ring;
  const int tid = threadIdx.x;
  const int l = tid & 63;
  const int wid = tid >> 6;   // 0..7
  const int q32 = l & 31;
  const int h2 = l >> 5;
  const int wh = blockIdx.x;
  const int qc = blockIdx.y;  // 0..1
  const int h = wh & 7;
  const int w = wh >> 3;
  _Float16* Qp = qkv + ((size_t)(w * 24 + h) << 15);
  const _Float16* Kp = qkv + ((size_t)(w * 24 + 8 + h) << 15);
  const _Float16* Vp = qkv + ((size_t)(w * 24 + 16 + h) << 15);
  const int qrow = qc * 256 + wid * 32 + q32;

  const size_t kSrc = (size_t)(l >> 3) * 128 + (size_t)((l & 7) ^ (l >> 3)) * 16;
  const int kof0 = ((0 * 2 + h2) ^ (q32 & 7)) << 4;
  const int kof1 = ((1 * 2 + h2) ^ (q32 & 7)) << 4;
  const int kof2 = ((2 * 2 + h2) ^ (q32 & 7)) << 4;
  const int kof3 = ((3 * 2 + h2) ^ (q32 & 7)) << 4;
  const int voff = 4096 + h2 * 1024 + q32 * 16;

#define ISSUE_SLOT(KT)                                                            \
  {                                                                               \
    char* sb = ringB + ((KT)&7) * 8192;                                           \
    if (wid < 4) {                                                                \
      GLL16((const char*)Kp + (size_t)(KT)*4096 + (size_t)wid * 1024 + kSrc,      \
            sb + wid * 1024);                                                     \
    } else {                                                                      \
      GLL16((const char*)Vp + (size_t)(KT)*4096 + (size_t)(wid - 4) * 1024 + l * 16, \
            sb + 4096 + (wid - 4) * 1024);                                        \
    }                                                                             \
  }

  half8_t qf[4];
#pragma unroll
  for (int j = 0; j < 4; ++j)
    qf[j] = *(const half8_t*)(Qp + (size_t)qrow * 64 + j * 16 + h2 * 8);
  asm volatile("s_waitcnt vmcnt(0)" ::: "memory");  // drain qf; ledger = slot DMAs only

  ISSUE_SLOT(0) ISSUE_SLOT(1) ISSUE_SLOT(2) ISSUE_SLOT(3)
  ISSUE_SLOT(4) ISSUE_SLOT(5) ISSUE_SLOT(6)  // outstanding: 7

  f32x16 o0 = {}, o1 = {};
  float m_run = -1e30f, lsum = 0.f;

#define AITER(KT, NW)                                                             \
  {                                                                               \
    asm volatile("s_waitcnt vmcnt(" NW ")" ::: "memory");                         \
    __builtin_amdgcn_sched_barrier(0);                                            \
    asm volatile("s_barrier" ::: "memory");                                       \
    if ((KT) + 7 < 16) ISSUE_SLOT((KT) + 7)                                       \
    char* sl = ringB + ((KT)&7) * 8192;                                           \
    half8_t kf0 = *(const half8_t*)(sl + q32 * 128 + kof0);                       \
    half8_t kf1 = *(const half8_t*)(sl + q32 * 128 + kof1);                       \
    half8_t kf2 = *(const half8_t*)(sl + q32 * 128 + kof2);                       \
    half8_t kf3 = *(const half8_t*)(sl + q32 * 128 + kof3);                       \
    __builtin_amdgcn_s_setprio(1);                                                \
    f32x16 s = {};                                                                \
    s = __builtin_amdgcn_mfma_f32_32x32x16_f16(kf0, qf[0], s, 0, 0, 0);           \
    s = __builtin_amdgcn_mfma_f32_32x32x16_f16(kf1, qf[1], s, 0, 0, 0);           \
    s = __builtin_amdgcn_mfma_f32_32x32x16_f16(kf2, qf[2], s, 0, 0, 0);           \
    s = __builtin_amdgcn_mfma_f32_32x32x16_f16(kf3, qf[3], s, 0, 0, 0);           \
    __builtin_amdgcn_s_setprio(0);                                                \
    float ma = fmaxf(fmaxf(s[0], s[1]), s[2]);                                    \
    float mb = fmaxf(fmaxf(s[3], s[4]), s[5]);                                    \
    float mc = fmaxf(fmaxf(s[6], s[7]), s[8]);                                    \
    float md = fmaxf(fmaxf(s[9], s[10]), s[11]);                                  \
    float me = fmaxf(fmaxf(s[12], s[13]), s[14]);                                 \
    float mf_ = fmaxf(fmaxf(ma, mb), mc);                                         \
    float mg = fmaxf(fmaxf(md, me), s[15]);                                       \
    float tmax = fmaxf(mf_, mg);                                                  \
    tmax = fmaxf(tmax, __shfl_xor(tmax, 32));                                     \
    if (!__all(tmax <= m_run + 11.5f)) {                                          \
      float mNew = fmaxf(m_run, tmax);                                            \
      float sc = fexp2(m_run - mNew);                                             \
      lsum *= sc;                                                                 \
      _Pragma("unroll") for (int r = 0; r < 16; ++r) { o0[r] *= sc; o1[r] *= sc; }\
      m_run = mNew;                                                               \
    }                                                                             \
    half8_t pf0, pf1;                                                             \
    float tsum = 0.f;                                                             \
    _Pragma("unroll") for (int e = 0; e < 4; ++e) {                               \
      float a0 = fexp2(s[2 * e] - m_run), a1 = fexp2(s[2 * e + 1] - m_run);       \
      tsum += a0 + a1;                                                            \
      ((half2_t*)&pf0)[e] =                                                       \
          __builtin_bit_cast(half2_t, __builtin_amdgcn_cvt_pkrtz(a0, a1));        \
    }                                                                             \
    _Pragma("unroll") for (int e = 0; e < 4; ++e) {                               \
      float a0 = fexp2(s[8 + 2 * e] - m_run), a1 = fexp2(s[9 + 2 * e] - m_run);   \
      tsum += a0 + a1;                                                            \
      ((half2_t*)&pf1)[e] =                                                       \
          __builtin_bit_cast(half2_t, __builtin_amdgcn_cvt_pkrtz(a0, a1));        \
    }                                                                             \
    tsum += __shfl_xor(tsum, 32);                                                 \
    lsum += tsum;                                                                 \
    half8_t vf0 = *(const half8_t*)(sl + voff);                                   \
    half8_t vf1 = *(const half8_t*)(sl + voff + 512);                             \
    half8_t vf2 = *(const half8_t*)(sl + voff + 2048);                            \
    half8_t vf3 = *(const half8_t*)(sl + voff + 2560);                            \
    __builtin_amdgcn_s_setprio(1);                                                \
    o0 = __builtin_amdgcn_mfma_f32_32x32x16_f16(vf0, pf0, o0, 0, 0, 0);           \
    o1 = __builtin_amdgcn_mfma_f32_32x32x16_f16(vf1, pf0, o1, 0, 0, 0);           \
    o0 = __builtin_amdgcn_mfma_f32_32x32x16_f16(vf2, pf1, o0, 0, 0, 0);           \
    o1 = __builtin_amdgcn_mfma_f32_32x32x16_f16(vf3, pf1, o1, 0, 0, 0);           \
    __builtin_amdgcn_s_setprio(0);                                                \
  }

  AITER(0, "6")  AITER(1, "6")  AITER(2, "6")  AITER(3, "6")
  AITER(4, "6")  AITER(5, "6")  AITER(6, "6")  AITER(7, "6")
  AITER(8, "6")  AITER(9, "6")  AITER(10, "5") AITER(11, "4")
  AITER(12, "3") AITER(13, "2") AITER(14, "1") AITER(15, "0")

  const float inv = 1.0f / lsum;
#pragma unroll
  for (int rq = 0; rq < 4; ++rq) {
    half4_t v0, v1;
#pragma unroll
    for (int i = 0; i < 4; ++i) {
      v0[i] = (_Float16)(o0[rq * 4 + i] * inv);
      v1[i] = (_Float16)(o1[rq * 4 + i] * inv);
    }
    *(half4_t*)(Qp + (size_t)qrow * 64 + 8 * rq + 4 * h2) = v0;
    *(half4_t*)(Qp + (size_t)qrow * 64 + 32 + 8 * rq + 4 * h2) = v1;
  }
}

// ---------------- GEMM2: out = attn_out @ Wproj + b, k-prefetched fragments ----------------
__global__ __launch_bounds__(256) void gemm2_proj(
    const _Float16* __restrict__ qkv,
    const _Float16* __restrict__ wpT,
    const float* __restrict__ bias,
    float* __restrict__ out) {
  const int tid = threadIdx.x, l = tid & 63;
  const int wid = tid >> 6, wr = wid >> 1, wc = wid & 1;
  const int lr = l & 15, lk8 = (l >> 4) * 8;
  const int m0 = blockIdx.x * 128, n0 = blockIdx.y * 128;
  size_t aBase[4];
#pragma unroll
  for (int mt = 0; mt < 4; ++mt) {
    int row = m0 + wr * 64 + mt * 16 + lr;
    int wL = row >> 9, n = row & 511;
    aBase[mt] = ((size_t)(wL * 24) << 15) + (size_t)n * 64 + lk8;
  }
  size_t bBase[4];
#pragma unroll
  for (int nt = 0; nt < 4; ++nt)
    bBase[nt] = (size_t)(n0 + wc * 64 + nt * 16 + lr) * 512 + lk8;

  half8_t a[4], b[4];
#pragma unroll
  for (int mt = 0; mt < 4; ++mt) a[mt] = *(const half8_t*)(qkv + aBase[mt]);
#pragma unroll
  for (int nt = 0; nt < 4; ++nt) b[nt] = *(const half8_t*)(wpT + bBase[nt]);

  f32x4 acc[4][4] = {};
#pragma unroll 2
  for (int ks = 0; ks < 16; ++ks) {
    half8_t an[4], bn[4];
    if (ks < 15) {
      const size_t aoff = (size_t)((ks + 1) >> 1) * 32768 + (size_t)((ks + 1) & 1) * 32;
#pragma unroll
      for (int mt = 0; mt < 4; ++mt) an[mt] = *(const half8_t*)(qkv + aBase[mt] + aoff);
#pragma unroll
      for (int nt = 0; nt < 4; ++nt) bn[nt] = *(const half8_t*)(wpT + bBase[nt] + (ks + 1) * 32);
    }
#pragma unroll
    for (int mt = 0; mt < 4; ++mt)
#pragma unroll
      for (int nt = 0; nt < 4; ++nt)
        acc[mt][nt] = __builtin_amdgcn_mfma_f32_16x16x32_f16(a[mt], b[nt], acc[mt][nt], 0, 0, 0);
#pragma unroll
    for (int i = 0; i < 4; ++i) { a[i] = an[i]; b[i] = bn[i]; }
  }
#pragma unroll
  for (int nt = 0; nt < 4; ++nt) {
    int col = n0 + wc * 64 + nt * 16 + lr;
    float bv = bias[col];
#pragma unroll
    for (int mt = 0; mt < 4; ++mt) {
      int row = m0 + wr * 64 + mt * 16 + ((l >> 4) << 2);
#pragma unroll
      for (int r = 0; r < 4; ++r)
        out[(size_t)(row + r) * 512 + col] = acc[mt][nt][r] + bv;
    }
  }
}

extern "C" void kernel_launch(void* const* d_in, const int* in_sizes, int n_in,
                              void* d_out, int out_size, void* d_ws, size_t ws_size,
                              hipStream_t stream) {
  const float* x = (const float*)d_in[0];
  const float* wqkv = (const float*)d_in[1];
  const float* bqkv = (const float*)d_in[2];
  const float* wproj = (const float*)d_in[3];
  const float* bproj = (const float*)d_in[4];
  float* out = (float*)d_out;

  _Float16* wqkvT = (_Float16*)d_ws;
  _Float16* wprojT = wqkvT + (size_t)TC * CDIM;
  _Float16* chunkws = wprojT + (size_t)CDIM * CDIM;
  const size_t fixed = ((size_t)TC * CDIM + (size_t)CDIM * CDIM) * sizeof(_Float16);
  const size_t perwin = ((size_t)NTOK * CDIM + (size_t)24 * 32768) * sizeof(_Float16);
  int nw = 64;
  while (nw > 1 && fixed + (size_t)nw * perwin > ws_size) nw >>= 1;

  prep_weights<<<dim3(256), 256, 0, stream>>>(wqkv, wproj, wqkvT, wprojT);
  for (int wbase = 0; wbase < NWIN; wbase += nw) {
    const float* xc = x + (size_t)wbase * NTOK * CDIM;
    float* oc = out + (size_t)wbase * NTOK * CDIM;
    _Float16* x16 = chunkws;
    _Float16* qkvws = chunkws + (size_t)nw * NTOK * CDIM;
    cvt_x<<<dim3(nw * 32), 256, 0, stream>>>(xc, x16);
    gemm1_qkv<<<dim3(nw * 4, 12), 256, 0, stream>>>(x16, wqkvT, bqkv, qkvws);
    attn_win<<<dim3(nw * 8, 2), 512, 0, stream>>>(qkvws);
    gemm2_proj<<<dim3(nw * 4, 4), 256, 0, stream>>>(qkvws, wprojT, bproj, oc);
  }
}

// Round 19
// 184.162 us; speedup vs baseline: 1.2082x; 1.2082x over previous
//
#include <hip/hip_runtime.h>
#include <hip/hip_bf16.h>

typedef _Float16 half8_t __attribute__((ext_vector_type(8)));
typedef _Float16 half4_t __attribute__((ext_vector_type(4)));
typedef _Float16 half2_t __attribute__((ext_vector_type(2)));
typedef float    f32x4   __attribute__((ext_vector_type(4)));
typedef float    f32x16  __attribute__((ext_vector_type(16)));

#define CDIM 512
#define NHEAD 8
#define HD 64
#define NTOK 512
#define NWIN 64
#define TC 1536  // 3*C

// raw v_exp_f32 (2^x); softmax inputs <= 11.5, large-negative underflows to 0.
__device__ __forceinline__ float fexp2(float x) {
  float r;
  asm("v_exp_f32 %0, %1" : "=v"(r) : "v"(x));
  return r;
}

// global->LDS direct DMA, 16B per lane, wave-uniform LDS base (m97 pattern)
#define GLL16(g, l)                                                        \
  __builtin_amdgcn_global_load_lds((const __attribute__((address_space(1))) void*)(g), \
                                   (__attribute__((address_space(3))) void*)(l), 16, 0, 0)

// ws panel layout: per (local window w): 24 panels of 32768 halfs (65536 B)
//   panel (w*24 + 0*8 + h): Q*log2e [n][d]
//   panel (w*24 + 1*8 + h): K  [n][d]
//   panel (w*24 + 2*8 + h): V key-permuted: [kg(32)][hh(2)][d(64)][e(8)]
//     key n -> kg=n>>4, hh=(n>>2)&1, e=(n&3)+4*((n>>3)&1)
// obuf / wprojT BLOCKED layout (for gemm2-v7 full-line staging): tile(rb,ks) =
//   rows [rb*16,+16) x k [ks*32,+32), contiguous 1024B:
//   halfs offset = rb*8192 + ks*512 + (row&15)*32 + (k&31).

// ---------------- x fp32 -> fp16 (linear, coalesced both sides) ----------------
__global__ __launch_bounds__(256) void cvt_x(const float* __restrict__ x,
                                             _Float16* __restrict__ x16, int n8) {
  int i = blockIdx.x * 256 + threadIdx.x;
  if (i < n8) {
    float4 v0 = *(const float4*)(x + (size_t)i * 8);
    float4 v1 = *(const float4*)(x + (size_t)i * 8 + 4);
    half8_t h = {(_Float16)v0.x, (_Float16)v0.y, (_Float16)v0.z, (_Float16)v0.w,
                 (_Float16)v1.x, (_Float16)v1.y, (_Float16)v1.z, (_Float16)v1.w};
    *(half8_t*)(x16 + (size_t)i * 8) = h;
  }
}

// ---------------- prep: wqkvT linear (for gemm1 v6b), wprojT BLOCKED (for gemm2 v7) ----------------
__global__ __launch_bounds__(256) void prep_weights(
    const float* __restrict__ wqkv, const float* __restrict__ wproj,
    _Float16* __restrict__ wqkvT, _Float16* __restrict__ wprojT) {
  __shared__ _Float16 T[64 * 65];
  int b = blockIdx.x;
  const float* src; _Float16* dst; int Cc, r0, c0; bool blocked;
  if (b < 192) {
    src = wqkv; dst = wqkvT; Cc = 1536; blocked = false;
    c0 = (b % 24) * 64; r0 = (b / 24) * 64;
  } else {
    b -= 192; src = wproj; dst = wprojT; Cc = 512; blocked = true;
    c0 = (b & 7) * 64; r0 = (b >> 3) * 64;
  }
  const int t = threadIdx.x;
#pragma unroll
  for (int i = 0; i < 16; ++i) {
    int idx = i * 256 + t, rr = idx >> 6, cc = idx & 63;
    T[rr * 65 + cc] = (_Float16)src[(size_t)(r0 + rr) * Cc + c0 + cc];
  }
  __syncthreads();
#pragma unroll
  for (int i = 0; i < 2; ++i) {
    int idx = i * 256 + t, ol = idx >> 3, c8 = idx & 7;
    half8_t vv;
#pragma unroll
    for (int e = 0; e < 8; ++e) vv[e] = T[(c8 * 8 + e) * 65 + ol];
    int o = c0 + ol, k = r0 + c8 * 8;
    if (blocked)
      *(half8_t*)(dst + (size_t)(o >> 4) * 8192 + (size_t)(k >> 5) * 512 +
                  (o & 15) * 32 + (k & 24)) = vv;
    else
      *(half8_t*)(dst + (size_t)o * 512 + k) = vv;
  }
}

// ---------------- GEMM1 v6b (r13-verified): 256x256 tile, 8 waves, BK=32, ring-4 ----------------
__global__ __launch_bounds__(512, 2) void gemm1_qkv(
    const _Float16* __restrict__ x16,
    const _Float16* __restrict__ wT,
    const float* __restrict__ bias,
    _Float16* __restrict__ qkv) {
  __shared__ __align__(16) char ring[4 * 32768];  // 128KB; epilogue reuses as C-tile
  char* ringB = ring;
  const int tid = threadIdx.x;
  const int l = tid & 63;
  const int wid = tid >> 6;            // 0..7
  const int wr = wid >> 2, wc = wid & 3;
  const int lr = l & 15, g = l >> 4;
  const int koff = ((g ^ ((lr >> 1) & 3)) << 4);
  const int m0 = blockIdx.x * 256;
  const int cb = blockIdx.y * 256;
  const int j = cb >> 9;

  const int srow4 = l >> 2;
  const int schk = (l & 3) ^ ((srow4 >> 1) & 3);
  const size_t aSrc = (size_t)(m0 + wid * 32 + srow4) * 1024 + ((size_t)schk << 4);
  const size_t bSrc = (size_t)(cb + wid * 32 + srow4) * 1024 + ((size_t)schk << 4);

#define ISSUE_G1(KS)                                                              \
  {                                                                               \
    char* sa = ringB + ((KS)&3) * 32768;                                          \
    char* sb = sa + 16384;                                                        \
    _Pragma("unroll") for (int i = 0; i < 2; ++i) {                               \
      GLL16((const char*)x16 + aSrc + (size_t)i * 16384 + (size_t)(KS)*64,        \
            sa + wid * 2048 + i * 1024);                                          \
      GLL16((const char*)wT + bSrc + (size_t)i * 16384 + (size_t)(KS)*64,         \
            sb + wid * 2048 + i * 1024);                                          \
    }                                                                             \
  }

  ISSUE_G1(0) ISSUE_G1(1) ISSUE_G1(2)

  f32x4 acc[8][4] = {};

#define GITER(KS, NW)                                                             \
  {                                                                               \
    asm volatile("s_waitcnt vmcnt(" NW ")" ::: "memory");                         \
    __builtin_amdgcn_sched_barrier(0);                                            \
    asm volatile("s_barrier" ::: "memory");                                       \
    if ((KS) + 3 < 16) ISSUE_G1((KS) + 3)                                         \
    char* sa = ringB + ((KS)&3) * 32768;                                          \
    char* sb = sa + 16384;                                                        \
    half8_t a[8], b[4];                                                           \
    _Pragma("unroll") for (int mt = 0; mt < 8; ++mt)                              \
        a[mt] = *(const half8_t*)(sa + (wr * 128 + mt * 16 + lr) * 64 + koff);    \
    _Pragma("unroll") for (int nt = 0; nt < 4; ++nt)                              \
        b[nt] = *(const half8_t*)(sb + (wc * 64 + nt * 16 + lr) * 64 + koff);     \
    __builtin_amdgcn_s_setprio(1);                                                \
    _Pragma("unroll") for (int mt = 0; mt < 8; ++mt)                              \
        _Pragma("unroll") for (int nt = 0; nt < 4; ++nt)                          \
            acc[mt][nt] =                                                         \
                __builtin_amdgcn_mfma_f32_16x16x32_f16(a[mt], b[nt], acc[mt][nt], 0, 0, 0); \
    __builtin_amdgcn_s_setprio(0);                                                \
  }

  GITER(0, "8")  GITER(1, "8")  GITER(2, "8")  GITER(3, "8")
  GITER(4, "8")  GITER(5, "8")  GITER(6, "8")  GITER(7, "8")
  GITER(8, "8")  GITER(9, "8")  GITER(10, "8") GITER(11, "8")
  GITER(12, "8") GITER(13, "8") GITER(14, "4") GITER(15, "0")

  if (j == 2) {  // V: key-permuted panels, 8B stores
#pragma unroll
    for (int nt = 0; nt < 4; ++nt) {
      const int ch = cb + wc * 64 + nt * 16 + lr;
      const int h = (ch >> 6) & 7, d = ch & 63;
      const float bvs = bias[ch];
#pragma unroll
      for (int mt = 0; mt < 8; ++mt) {
        const int row = m0 + wr * 128 + mt * 16 + g * 4;
        const int wL = row >> 9, n = row & 511;
        _Float16* panel = qkv + ((size_t)(wL * 24 + 16 + h) << 15);
        const int kg = n >> 4, hh = (n >> 2) & 1, e4 = (n & 8) >> 1;
        half4_t pk = {(_Float16)(acc[mt][nt][0] + bvs), (_Float16)(acc[mt][nt][1] + bvs),
                      (_Float16)(acc[mt][nt][2] + bvs), (_Float16)(acc[mt][nt][3] + bvs)};
        *(half4_t*)(panel + ((size_t)(kg * 2 + hh) * 64 + d) * 8 + e4) = pk;
      }
    }
  } else {  // Q/K: acc -> swizzled LDS C-tile -> coalesced 16B stores
    __syncthreads();
    const float scl = (j == 0) ? 1.44269504f : 1.0f;
    char* CB = ringB;
#pragma unroll
    for (int nt = 0; nt < 4; ++nt) {
      const int chl = wc * 64 + nt * 16 + lr;
      const float bvs = bias[cb + chl];
#pragma unroll
      for (int mt = 0; mt < 8; ++mt) {
#pragma unroll
        for (int r = 0; r < 4; ++r) {
          int nl = wr * 128 + mt * 16 + g * 4 + r;
          *(_Float16*)(CB + nl * 512 + ((chl * 2) ^ ((nl & 7) << 5))) =
              (_Float16)((acc[mt][nt][r] + bvs) * scl);
        }
      }
    }
    __syncthreads();
#pragma unroll
    for (int i = 0; i < 16; ++i) {
      int idx = i * 512 + tid, nl = idx >> 5, c8 = idx & 31;
      half8_t vv = *(const half8_t*)(CB + nl * 512 + ((c8 * 16) ^ ((nl & 7) << 5)));
      int chg = cb + c8 * 8;
      int h = (chg >> 6) & 7, d = chg & 63;
      int ng = m0 + nl, wL = ng >> 9, nn = ng & 511;
      _Float16* panel = qkv + ((size_t)(wL * 24 + j * 8 + h) << 15);
      *(half8_t*)(panel + (size_t)nn * 64 + d) = vv;
    }
  }
}

// ---------------- attention (r13-verified ring-4 8-wave) + BLOCKED obuf epilogue ----------------
// grid = dim3(nw*8, 2). Block = 8 waves on one (w,h) half (256 q-rows); ring 4 x 8KB.
__global__ __launch_bounds__(512) void attn_win(const _Float16* __restrict__ qkv,
                                                _Float16* __restrict__ obuf) {
  __shared__ __align__(16) char ring[4 * 8192];
  char* ringB = ring;
  const int tid = threadIdx.x;
  const int l = tid & 63;
  const int wid = tid >> 6;   // 0..7
  const int q32 = l & 31;
  const int h2 = l >> 5;
  const int wh = blockIdx.x;
  const int qc = blockIdx.y;  // 0..1
  const int h = wh & 7;
  const int w = wh >> 3;
  const _Float16* Qp = qkv + ((size_t)(w * 24 + h) << 15);
  const _Float16* Kp = qkv + ((size_t)(w * 24 + 8 + h) << 15);
  const _Float16* Vp = qkv + ((size_t)(w * 24 + 16 + h) << 15);
  const int qrow = qc * 256 + wid * 32 + q32;

  const size_t kSrc = (size_t)(l >> 3) * 128 + (size_t)((l & 7) ^ (l >> 3)) * 16;
  const int kof0 = ((0 * 2 + h2) ^ (q32 & 7)) << 4;
  const int kof1 = ((1 * 2 + h2) ^ (q32 & 7)) << 4;
  const int kof2 = ((2 * 2 + h2) ^ (q32 & 7)) << 4;
  const int kof3 = ((3 * 2 + h2) ^ (q32 & 7)) << 4;
  const int voff = 4096 + h2 * 1024 + q32 * 16;

#define ISSUE_SLOT(KT)                                                            \
  {                                                                               \
    char* sb = ringB + ((KT)&3) * 8192;                                           \
    if (wid < 4) {                                                                \
      GLL16((const char*)Kp + (size_t)(KT)*4096 + (size_t)wid * 1024 + kSrc,      \
            sb + wid * 1024);                                                     \
    } else {                                                                      \
      GLL16((const char*)Vp + (size_t)(KT)*4096 + (size_t)(wid - 4) * 1024 + l * 16, \
            sb + 4096 + (wid - 4) * 1024);                                        \
    }                                                                             \
  }

  half8_t qf[4];
#pragma unroll
  for (int j = 0; j < 4; ++j)
    qf[j] = *(const half8_t*)(Qp + (size_t)qrow * 64 + j * 16 + h2 * 8);
  asm volatile("s_waitcnt vmcnt(0)" ::: "memory");  // drain qf; ledger = slot DMAs only

  ISSUE_SLOT(0) ISSUE_SLOT(1) ISSUE_SLOT(2)  // outstanding: 3

  f32x16 o0 = {}, o1 = {};
  float m_run = -1e30f, lsum = 0.f;

#define AITER(KT, NW)                                                             \
  {                                                                               \
    asm volatile("s_waitcnt vmcnt(" NW ")" ::: "memory");                         \
    __builtin_amdgcn_sched_barrier(0);                                            \
    asm volatile("s_barrier" ::: "memory");                                       \
    if ((KT) + 3 < 16) ISSUE_SLOT((KT) + 3)                                       \
    char* sl = ringB + ((KT)&3) * 8192;                                           \
    half8_t kf0 = *(const half8_t*)(sl + q32 * 128 + kof0);                       \
    half8_t kf1 = *(const half8_t*)(sl + q32 * 128 + kof1);                       \
    half8_t kf2 = *(const half8_t*)(sl + q32 * 128 + kof2);                       \
    half8_t kf3 = *(const half8_t*)(sl + q32 * 128 + kof3);                       \
    __builtin_amdgcn_s_setprio(1);                                                \
    f32x16 s = {};                                                                \
    s = __builtin_amdgcn_mfma_f32_32x32x16_f16(kf0, qf[0], s, 0, 0, 0);           \
    s = __builtin_amdgcn_mfma_f32_32x32x16_f16(kf1, qf[1], s, 0, 0, 0);           \
    s = __builtin_amdgcn_mfma_f32_32x32x16_f16(kf2, qf[2], s, 0, 0, 0);           \
    s = __builtin_amdgcn_mfma_f32_32x32x16_f16(kf3, qf[3], s, 0, 0, 0);           \
    __builtin_amdgcn_s_setprio(0);                                                \
    float ma = fmaxf(fmaxf(s[0], s[1]), s[2]);                                    \
    float mb = fmaxf(fmaxf(s[3], s[4]), s[5]);                                    \
    float mc = fmaxf(fmaxf(s[6], s[7]), s[8]);                                    \
    float md = fmaxf(fmaxf(s[9], s[10]), s[11]);                                  \
    float me = fmaxf(fmaxf(s[12], s[13]), s[14]);                                 \
    float mf_ = fmaxf(fmaxf(ma, mb), mc);                                         \
    float mg = fmaxf(fmaxf(md, me), s[15]);                                       \
    float tmax = fmaxf(mf_, mg);                                                  \
    tmax = fmaxf(tmax, __shfl_xor(tmax, 32));                                     \
    if (!__all(tmax <= m_run + 11.5f)) {                                          \
      float mNew = fmaxf(m_run, tmax);                                            \
      float sc = fexp2(m_run - mNew);                                             \
      lsum *= sc;                                                                 \
      _Pragma("unroll") for (int r = 0; r < 16; ++r) { o0[r] *= sc; o1[r] *= sc; }\
      m_run = mNew;                                                               \
    }                                                                             \
    half8_t pf0, pf1;                                                             \
    float tsum = 0.f;                                                             \
    _Pragma("unroll") for (int e = 0; e < 4; ++e) {                               \
      float a0 = fexp2(s[2 * e] - m_run), a1 = fexp2(s[2 * e + 1] - m_run);       \
      tsum += a0 + a1;                                                            \
      ((half2_t*)&pf0)[e] =                                                       \
          __builtin_bit_cast(half2_t, __builtin_amdgcn_cvt_pkrtz(a0, a1));        \
    }                                                                             \
    _Pragma("unroll") for (int e = 0; e < 4; ++e) {                               \
      float a0 = fexp2(s[8 + 2 * e] - m_run), a1 = fexp2(s[9 + 2 * e] - m_run);   \
      tsum += a0 + a1;                                                            \
      ((half2_t*)&pf1)[e] =                                                       \
          __builtin_bit_cast(half2_t, __builtin_amdgcn_cvt_pkrtz(a0, a1));        \
    }                                                                             \
    tsum += __shfl_xor(tsum, 32);                                                 \
    lsum += tsum;                                                                 \
    half8_t vf0 = *(const half8_t*)(sl + voff);                                   \
    half8_t vf1 = *(const half8_t*)(sl + voff + 512);                             \
    half8_t vf2 = *(const half8_t*)(sl + voff + 2048);                            \
    half8_t vf3 = *(const half8_t*)(sl + voff + 2560);                            \
    __builtin_amdgcn_s_setprio(1);                                                \
    o0 = __builtin_amdgcn_mfma_f32_32x32x16_f16(vf0, pf0, o0, 0, 0, 0);           \
    o1 = __builtin_amdgcn_mfma_f32_32x32x16_f16(vf1, pf0, o1, 0, 0, 0);           \
    o0 = __builtin_amdgcn_mfma_f32_32x32x16_f16(vf2, pf1, o0, 0, 0, 0);           \
    o1 = __builtin_amdgcn_mfma_f32_32x32x16_f16(vf3, pf1, o1, 0, 0, 0);           \
    __builtin_amdgcn_s_setprio(0);                                                \
  }

  AITER(0, "2")  AITER(1, "2")  AITER(2, "2")  AITER(3, "2")
  AITER(4, "2")  AITER(5, "2")  AITER(6, "2")  AITER(7, "2")
  AITER(8, "2")  AITER(9, "2")  AITER(10, "2") AITER(11, "2")
  AITER(12, "2") AITER(13, "2") AITER(14, "1") AITER(15, "0")

  // epilogue: write O into BLOCKED obuf tiles (row R = w*512+qrow, ch = h*64+d)
  //   addr = (R>>4)*8192 + (h*2+dt)*512 + (R&15)*32 + 8*rq + 4*h2
  const float inv = 1.0f / lsum;
  const size_t rbase = ((size_t)(w * 32 + qc * 16 + wid * 2 + (q32 >> 4))) * 8192 +
                       (size_t)(q32 & 15) * 32 + 4 * h2;
#pragma unroll
  for (int rq = 0; rq < 4; ++rq) {
    half4_t v0, v1;
#pragma unroll
    for (int i = 0; i < 4; ++i) {
      v0[i] = (_Float16)(o0[rq * 4 + i] * inv);
      v1[i] = (_Float16)(o1[rq * 4 + i] * inv);
    }
    *(half4_t*)(obuf + rbase + (size_t)(h * 2 + 0) * 512 + 8 * rq) = v0;
    *(half4_t*)(obuf + rbase + (size_t)(h * 2 + 1) * 512 + 8 * rq) = v1;
  }
}

// ---------------- GEMM2 v7: clone of gemm1-v7 pipeline; blocked obuf @ blocked wprojT ----------------
__global__ __launch_bounds__(256, 3) void gemm2_proj(
    const _Float16* __restrict__ obuf,   // blocked [rows][512]
    const _Float16* __restrict__ wpT,    // blocked [512][512]
    const float* __restrict__ bias,
    float* __restrict__ out) {
  __shared__ __align__(16) char ring[3 * 16384];  // 48KB
  char* ringB = ring;
  const int tid = threadIdx.x;
  const int l = tid & 63;
  const int wid = tid >> 6;               // 0..3
  const int wr = wid >> 1, wc = wid & 1;  // 2M x 2N waves; per-wave 64x64 output
  const int lr = l & 15, g = l >> 4;
  const int koff = ((g ^ ((lr >> 1) & 3)) << 4);
  const int m0 = blockIdx.x * 128;
  const int n0 = blockIdx.y * 128;

  const int r4 = l >> 2;
  const int schk = (l & 3) ^ ((r4 >> 1) & 3);
  const size_t laneT = (size_t)r4 * 64 + (size_t)schk * 16;
  const size_t aTile = ((size_t)(blockIdx.x * 8 + wid * 2)) * 16384 + laneT;
  const size_t bTile = ((size_t)(blockIdx.y * 8 + wid * 2)) * 16384 + laneT;

#define ISSUE_G2(KS)                                                              \
  {                                                                               \
    char* sa = ringB + ((KS) % 3) * 16384;                                        \
    char* sbB = sa + 8192;                                                        \
    _Pragma("unroll") for (int i = 0; i < 2; ++i) {                               \
      GLL16((const char*)obuf + aTile + (size_t)i * 16384 + (size_t)(KS)*1024,    \
            sa + wid * 2048 + i * 1024);                                          \
      GLL16((const char*)wpT + bTile + (size_t)i * 16384 + (size_t)(KS)*1024,     \
            sbB + wid * 2048 + i * 1024);                                         \
    }                                                                             \
  }

  ISSUE_G2(0) ISSUE_G2(1)  // outstanding: 8 (4/slot/thread)

  f32x4 acc[4][4] = {};

#define G2ITER(KS, NW)                                                            \
  {                                                                               \
    asm volatile("s_waitcnt vmcnt(" NW ")" ::: "memory");                         \
    __builtin_amdgcn_sched_barrier(0);                                            \
    asm volatile("s_barrier" ::: "memory");                                       \
    if ((KS) + 2 < 16) ISSUE_G2((KS) + 2)                                         \
    char* sa = ringB + ((KS) % 3) * 16384;                                        \
    char* sbB = sa + 8192;                                                        \
    half8_t a[4], b[4];                                                           \
    _Pragma("unroll") for (int mt = 0; mt < 4; ++mt)                              \
        a[mt] = *(const half8_t*)(sa + (wr * 64 + mt * 16 + lr) * 64 + koff);     \
    _Pragma("unroll") for (int nt = 0; nt < 4; ++nt)                              \
        b[nt] = *(const half8_t*)(sbB + (wc * 64 + nt * 16 + lr) * 64 + koff);    \
    __builtin_amdgcn_s_setprio(1);                                                \
    _Pragma("unroll") for (int mt = 0; mt < 4; ++mt)                              \
        _Pragma("unroll") for (int nt = 0; nt < 4; ++nt)                          \
            acc[mt][nt] =                                                         \
                __builtin_amdgcn_mfma_f32_16x16x32_f16(a[mt], b[nt], acc[mt][nt], 0, 0, 0); \
    __builtin_amdgcn_s_setprio(0);                                                \
  }

  G2ITER(0, "4")  G2ITER(1, "4")  G2ITER(2, "4")  G2ITER(3, "4")
  G2ITER(4, "4")  G2ITER(5, "4")  G2ITER(6, "4")  G2ITER(7, "4")
  G2ITER(8, "4")  G2ITER(9, "4")  G2ITER(10, "4") G2ITER(11, "4")
  G2ITER(12, "4") G2ITER(13, "4") G2ITER(14, "4") G2ITER(15, "0")

#pragma unroll
  for (int nt = 0; nt < 4; ++nt) {
    int col = n0 + wc * 64 + nt * 16 + lr;
    float bv = bias[col & 511];
#pragma unroll
    for (int mt = 0; mt < 4; ++mt) {
      int row = m0 + wr * 64 + mt * 16 + g * 4;
#pragma unroll
      for (int r = 0; r < 4; ++r)
        out[(size_t)(row + r) * 512 + col] = acc[mt][nt][r] + bv;
    }
  }
}

extern "C" void kernel_launch(void* const* d_in, const int* in_sizes, int n_in,
                              void* d_out, int out_size, void* d_ws, size_t ws_size,
                              hipStream_t stream) {
  const float* x = (const float*)d_in[0];
  const float* wqkv = (const float*)d_in[1];
  const float* bqkv = (const float*)d_in[2];
  const float* wproj = (const float*)d_in[3];
  const float* bproj = (const float*)d_in[4];
  float* out = (float*)d_out;

  _Float16* wqkvT = (_Float16*)d_ws;
  _Float16* wprojT = wqkvT + (size_t)TC * CDIM;
  _Float16* chunkws = wprojT + (size_t)CDIM * CDIM;
  const size_t fixed = ((size_t)TC * CDIM + (size_t)CDIM * CDIM) * sizeof(_Float16);
  // per window: x16 (512*512) + qkv panels (24*32768) + obuf (512*512) halfs
  const size_t perwin =
      ((size_t)NTOK * CDIM + (size_t)24 * 32768 + (size_t)NTOK * CDIM) * sizeof(_Float16);
  int nw = 64;
  while (nw > 1 && fixed + (size_t)nw * perwin > ws_size) nw >>= 1;

  prep_weights<<<dim3(256), 256, 0, stream>>>(wqkv, wproj, wqkvT, wprojT);
  for (int wbase = 0; wbase < NWIN; wbase += nw) {
    const float* xc = x + (size_t)wbase * NTOK * CDIM;
    float* oc = out + (size_t)wbase * NTOK * CDIM;
    _Float16* x16 = chunkws;
    _Float16* qkvws = chunkws + (size_t)nw * NTOK * CDIM;
    _Float16* obuf = qkvws + (size_t)nw * 24 * 32768;
    const int n8 = nw * NTOK * CDIM / 8;
    cvt_x<<<dim3((n8 + 255) / 256), 256, 0, stream>>>(xc, x16, n8);
    gemm1_qkv<<<dim3(nw * 2, 6), 512, 0, stream>>>(x16, wqkvT, bqkv, qkvws);
    attn_win<<<dim3(nw * 8, 2), 512, 0, stream>>>(qkvws, obuf);
    gemm2_proj<<<dim3(nw * 4, 4), 256, 0, stream>>>(obuf, wprojT, bproj, oc);
  }
}